// Round 4
// baseline (319.334 us; speedup 1.0000x reference)
//
#include <hip/hip_runtime.h>

// Clifford Cl(3,0) geometric product. Streaming: 268 MB read + 134 MB write.
//
// R2/R3 results: shuffle version and x4-MLP-unrolled version both ~113 us,
// 2.35 TB/s HBM, VALU 17% -> per-wave MLP is not the limit; memory-path cap.
//
// R4 theory (retry; R4 failed to compile: __builtin_nontemporal_store rejects
// HIP_vector_type float4 -> store via native ext_vector_type(4)):
// FETCH_SIZE == WRITE_SIZE == 134 MB is the tell. Working set a+b+out =
// 402 MB thrashes the 256 MB L3; the out stream allocates in L3 every
// dispatch, evicting a/b. Fix: NONTEMPORAL stores -> out bypasses L2/L3
// allocation: no RFO, no eviction. a+b (~268 MB) then ~fit in L3, reads
// become L3 hits, HBM carries mostly the write stream.

typedef float nfloat4 __attribute__((ext_vector_type(4)));

__device__ __forceinline__ void nt_store(float4 v, float4* p) {
    nfloat4 nv = {v.x, v.y, v.z, v.w};
    __builtin_nontemporal_store(nv, (nfloat4*)p);
}

__device__ __forceinline__ float4 clifford_half(float4 va, float4 vb, bool hi) {
    // Partner lane's halves via xor-1 shuffle (DPP quad-perm, no LDS).
    float4 pa, pb;
    pa.x = __shfl_xor(va.x, 1); pa.y = __shfl_xor(va.y, 1);
    pa.z = __shfl_xor(va.z, 1); pa.w = __shfl_xor(va.w, 1);
    pb.x = __shfl_xor(vb.x, 1); pb.y = __shfl_xor(vb.y, 1);
    pb.z = __shfl_xor(vb.z, 1); pb.w = __shfl_xor(vb.w, 1);

    float A0 = hi ? pa.x : va.x, A1 = hi ? pa.y : va.y;
    float A2 = hi ? pa.z : va.z, A3 = hi ? pa.w : va.w;
    float A4 = hi ? va.x : pa.x, A5 = hi ? va.y : pa.y;
    float A6 = hi ? va.z : pa.z, A7 = hi ? va.w : pa.w;
    float B0 = hi ? pb.x : vb.x, B1 = hi ? pb.y : vb.y;
    float B2 = hi ? pb.z : vb.z, B3 = hi ? pb.w : vb.w;
    float B4 = hi ? vb.x : pb.x, B5 = hi ? vb.y : pb.y;
    float B6 = hi ? vb.z : pb.z, B7 = hi ? vb.w : pb.w;

    float c0 = A0*B0 + A1*B1 + A2*B2 + A3*B3 - A4*B4 - A5*B5 - A6*B6 - A7*B7;
    float c1 = A0*B1 + A1*B0 - A2*B4 + A4*B2 - A3*B5 + A5*B3 - A6*B7 - A7*B6;
    float c2 = A0*B2 + A2*B0 + A1*B4 - A4*B1 - A3*B6 + A6*B3 + A5*B7 + A7*B5;
    float c3 = A0*B3 + A3*B0 + A1*B5 - A5*B1 + A2*B6 - A6*B2 - A4*B7 - A7*B4;
    float c4 = A0*B4 + A4*B0 + A1*B2 - A2*B1 - A5*B6 + A6*B5 + A3*B7 + A7*B3;
    float c5 = A0*B5 + A5*B0 + A1*B3 - A3*B1 + A4*B6 - A6*B4 - A2*B7 - A7*B2;
    float c6 = A0*B6 + A6*B0 + A2*B3 - A3*B2 - A4*B5 + A5*B4 + A1*B7 + A7*B1;
    float c7 = A0*B7 + A7*B0 + A1*B6 + A6*B1 - A2*B5 - A5*B2 + A3*B4 + A4*B3;

    return hi ? make_float4(c4, c5, c6, c7) : make_float4(c0, c1, c2, c3);
}

__global__ __launch_bounds__(256) void CliffordProduct_85452669321821_kernel(
    const float4* __restrict__ a, const float4* __restrict__ b,
    float4* __restrict__ out, int n4) {
    const bool hi = (threadIdx.x & 1);          // odd lane = high half (e4..e7)
    const int tileStride = gridDim.x * 1024;     // 4 x 256 float4 per block

    for (int base = blockIdx.x * 1024 + threadIdx.x; base < n4;
         base += tileStride) {
        if (base + 768 < n4) {
            float4 va0 = a[base];       float4 va1 = a[base + 256];
            float4 va2 = a[base + 512]; float4 va3 = a[base + 768];
            float4 vb0 = b[base];       float4 vb1 = b[base + 256];
            float4 vb2 = b[base + 512]; float4 vb3 = b[base + 768];

            // Nontemporal: bypass L2/L3 allocation for the write stream.
            nt_store(clifford_half(va0, vb0, hi), &out[base]);
            nt_store(clifford_half(va1, vb1, hi), &out[base + 256]);
            nt_store(clifford_half(va2, vb2, hi), &out[base + 512]);
            nt_store(clifford_half(va3, vb3, hi), &out[base + 768]);
        } else {
            // Tail: pairs (2k,2k+1) share the bounds check (n4 even, idx
            // parity matches lane parity), so shuffles stay pair-safe.
            #pragma unroll
            for (int u = 0; u < 4; ++u) {
                int idx = base + 256 * u;
                if (idx < n4)
                    nt_store(clifford_half(a[idx], b[idx], hi), &out[idx]);
            }
        }
    }
}

extern "C" void kernel_launch(void* const* d_in, const int* in_sizes, int n_in,
                              void* d_out, int out_size, void* d_ws, size_t ws_size,
                              hipStream_t stream) {
    const float4* a = (const float4*)d_in[0];
    const float4* b = (const float4*)d_in[1];
    float4* out = (float4*)d_out;
    int n4 = in_sizes[0] / 4;  // total float4 elements (2 per multivector)

    int blocks = (n4 + 1023) / 1024;   // 1024 float4 per block-tile
    if (blocks > 2048) blocks = 2048;  // grid-stride beyond 8 blocks/CU
    CliffordProduct_85452669321821_kernel<<<blocks, 256, 0, stream>>>(a, b, out, n4);
}

// Round 5
// 317.486 us; speedup vs baseline: 1.0058x; 1.0058x over previous
//
#include <hip/hip_runtime.h>
#include <stdint.h>

// Clifford Cl(3,0) geometric product. Streaming: 268 MB read + 134 MB write.
//
// History: LDS-staged, shuffle, shuffle+x4-MLP all ~113 us @ 2.37 TB/s HBM,
// VALU 17%, occ >50%, FETCH == WRITE == exactly 134 MB. R4's
// __builtin_nontemporal_store (nt bit only): FETCH unchanged, time WORSE
// (129 us) -> plain nt is an L2 hint, doesn't reach MALL policy; reverted.
//
// R5 theory: FETCH == exactly one array (134 MB, stable to 5 digits) is
// structural, not a ~50% hit rate: it is write-allocate/RFO for `out` at the
// Infinity Cache, with a/b nearly fully L3-resident across dispatches.
// Fix under test: TRUE streaming stores -- inline asm global_store_dwordx4
// with sc0 sc1 nt (system scope + non-temporal, full cache bypass). out stops
// allocating anywhere; MALL then holds a+b (268 vs 256 MB -> >90% read hit);
// HBM carries the write stream + small read residue.
//
// Also: one tile per block (8192 blocks, no grid-stride) so stores are the
// final VMEM ops before endpgm -- in-order vmcnt never makes a wave wait on
// store acks before its loads. Final s_waitcnt vmcnt(0) drains the asm
// stores (compiler doesn't track them).

typedef float nfloat4 __attribute__((ext_vector_type(4)));

__device__ __forceinline__ void stream_store(float4* p, float4 v) {
    nfloat4 nv = {v.x, v.y, v.z, v.w};
    // addr-first, data-second; sc0 sc1 nt = system-scope non-temporal.
    // No "memory" clobber: value dep keeps ordering vs the compute; letting
    // the compiler move unrelated loads across the store is desirable.
    asm volatile("global_store_dwordx4 %0, %1, off sc0 sc1 nt"
                 :
                 : "v"((uint64_t)(uintptr_t)p), "v"(nv));
}

__device__ __forceinline__ float4 clifford_half(float4 va, float4 vb, bool hi) {
    // Partner lane's halves via xor-1 shuffle (DPP quad-perm, no LDS).
    float4 pa, pb;
    pa.x = __shfl_xor(va.x, 1); pa.y = __shfl_xor(va.y, 1);
    pa.z = __shfl_xor(va.z, 1); pa.w = __shfl_xor(va.w, 1);
    pb.x = __shfl_xor(vb.x, 1); pb.y = __shfl_xor(vb.y, 1);
    pb.z = __shfl_xor(vb.z, 1); pb.w = __shfl_xor(vb.w, 1);

    float A0 = hi ? pa.x : va.x, A1 = hi ? pa.y : va.y;
    float A2 = hi ? pa.z : va.z, A3 = hi ? pa.w : va.w;
    float A4 = hi ? va.x : pa.x, A5 = hi ? va.y : pa.y;
    float A6 = hi ? va.z : pa.z, A7 = hi ? va.w : pa.w;
    float B0 = hi ? pb.x : vb.x, B1 = hi ? pb.y : vb.y;
    float B2 = hi ? pb.z : vb.z, B3 = hi ? pb.w : vb.w;
    float B4 = hi ? vb.x : pb.x, B5 = hi ? vb.y : pb.y;
    float B6 = hi ? vb.z : pb.z, B7 = hi ? vb.w : pb.w;

    float c0 = A0*B0 + A1*B1 + A2*B2 + A3*B3 - A4*B4 - A5*B5 - A6*B6 - A7*B7;
    float c1 = A0*B1 + A1*B0 - A2*B4 + A4*B2 - A3*B5 + A5*B3 - A6*B7 - A7*B6;
    float c2 = A0*B2 + A2*B0 + A1*B4 - A4*B1 - A3*B6 + A6*B3 + A5*B7 + A7*B5;
    float c3 = A0*B3 + A3*B0 + A1*B5 - A5*B1 + A2*B6 - A6*B2 - A4*B7 - A7*B4;
    float c4 = A0*B4 + A4*B0 + A1*B2 - A2*B1 - A5*B6 + A6*B5 + A3*B7 + A7*B3;
    float c5 = A0*B5 + A5*B0 + A1*B3 - A3*B1 + A4*B6 - A6*B4 - A2*B7 - A7*B2;
    float c6 = A0*B6 + A6*B0 + A2*B3 - A3*B2 - A4*B5 + A5*B4 + A1*B7 + A7*B1;
    float c7 = A0*B7 + A7*B0 + A1*B6 + A6*B1 - A2*B5 - A5*B2 + A3*B4 + A4*B3;

    return hi ? make_float4(c4, c5, c6, c7) : make_float4(c0, c1, c2, c3);
}

__global__ __launch_bounds__(256) void CliffordProduct_85452669321821_kernel(
    const float4* __restrict__ a, const float4* __restrict__ b,
    float4* __restrict__ out, int n4) {
    const bool hi = (threadIdx.x & 1);       // odd lane = high half (e4..e7)
    const int base = blockIdx.x * 1024 + threadIdx.x;  // 4 x 256 float4/block

    if (base + 768 < n4) {
        // All 8 loads issued before any use; stores are the last VMEM ops.
        float4 va0 = a[base];       float4 va1 = a[base + 256];
        float4 va2 = a[base + 512]; float4 va3 = a[base + 768];
        float4 vb0 = b[base];       float4 vb1 = b[base + 256];
        float4 vb2 = b[base + 512]; float4 vb3 = b[base + 768];

        stream_store(&out[base],       clifford_half(va0, vb0, hi));
        stream_store(&out[base + 256], clifford_half(va1, vb1, hi));
        stream_store(&out[base + 512], clifford_half(va2, vb2, hi));
        stream_store(&out[base + 768], clifford_half(va3, vb3, hi));
    } else {
        // Tail: pairs (2k,2k+1) share the bounds check (n4 even, idx parity
        // matches lane parity), so shuffles stay pair-safe.
        #pragma unroll
        for (int u = 0; u < 4; ++u) {
            int idx = base + 256 * u;
            if (idx < n4) stream_store(&out[idx], clifford_half(a[idx], b[idx], hi));
        }
    }
    // Drain the asm stores the compiler doesn't know about.
    asm volatile("s_waitcnt vmcnt(0)");
}

extern "C" void kernel_launch(void* const* d_in, const int* in_sizes, int n_in,
                              void* d_out, int out_size, void* d_ws, size_t ws_size,
                              hipStream_t stream) {
    const float4* a = (const float4*)d_in[0];
    const float4* b = (const float4*)d_in[1];
    float4* out = (float4*)d_out;
    int n4 = in_sizes[0] / 4;          // total float4 elements (2 per mv)
    int blocks = (n4 + 1023) / 1024;   // one 1024-float4 tile per block
    CliffordProduct_85452669321821_kernel<<<blocks, 256, 0, stream>>>(a, b, out, n4);
}

// Round 6
// 304.895 us; speedup vs baseline: 1.0474x; 1.0413x over previous
//
#include <hip/hip_runtime.h>
#include <stdint.h>

// Clifford Cl(3,0) geometric product. Streaming: 268 MB read + 134 MB write.
//
// History: LDS / shuffle / "unrolled" all ~113 us @ 2.37 TB/s HBM. nt stores
// (R4) and sc0+sc1+nt stores (R5): FETCH unchanged, slower -> cache-policy
// bits don't reach MALL allocation; reverted to plain stores.
// FETCH == exactly one array (134 MB) every dispatch = capacity partition
// (MALL holds out + half of a/b); traffic is not reducible from the kernel.
//
// R6: the R2 "MLP null" was a false negative: VGPR=36 proves the compiler
// re-interleaved the 8 loads with consumers (8 live float4 = 32 VGPR data
// minimum), so per-wave MLP stayed ~2. This round forces 8-deep MLP by
// construction: 8 inline-asm global_load_dwordx4 issued back-to-back
// (asm volatiles keep issue order), then counted s_waitcnt vmcnt(N) drain
// (consume pair k without waiting on younger loads/stores), each wait
// followed by sched_barrier(0) (rule #18: "memory" clobber does not order
// register-only consumers). 8 KB in flight per wave, ~256 KB per CU.

typedef float nfloat4 __attribute__((ext_vector_type(4)));

__device__ __forceinline__ nfloat4 gload(const float4* __restrict__ p,
                                         uint32_t voff) {
    nfloat4 r;
    // p is a uniform kernel arg -> SGPR pair base; voff = per-lane byte off.
    asm volatile("global_load_dwordx4 %0, %1, %2"
                 : "=v"(r)
                 : "v"(voff), "s"(p));
    return r;
}

#define WAIT_VM(N)                                        \
    asm volatile("s_waitcnt vmcnt(" #N ")" ::: "memory"); \
    __builtin_amdgcn_sched_barrier(0)

__device__ __forceinline__ float4 clifford_half(nfloat4 va, nfloat4 vb, bool hi) {
    // Partner lane's halves via xor-1 shuffle (DPP quad-perm, no LDS).
    float pax = __shfl_xor(va.x, 1), pay = __shfl_xor(va.y, 1);
    float paz = __shfl_xor(va.z, 1), paw = __shfl_xor(va.w, 1);
    float pbx = __shfl_xor(vb.x, 1), pby = __shfl_xor(vb.y, 1);
    float pbz = __shfl_xor(vb.z, 1), pbw = __shfl_xor(vb.w, 1);

    float A0 = hi ? pax : va.x, A1 = hi ? pay : va.y;
    float A2 = hi ? paz : va.z, A3 = hi ? paw : va.w;
    float A4 = hi ? va.x : pax, A5 = hi ? va.y : pay;
    float A6 = hi ? va.z : paz, A7 = hi ? va.w : paw;
    float B0 = hi ? pbx : vb.x, B1 = hi ? pby : vb.y;
    float B2 = hi ? pbz : vb.z, B3 = hi ? pbw : vb.w;
    float B4 = hi ? vb.x : pbx, B5 = hi ? vb.y : pby;
    float B6 = hi ? vb.z : pbz, B7 = hi ? vb.w : pbw;

    float c0 = A0*B0 + A1*B1 + A2*B2 + A3*B3 - A4*B4 - A5*B5 - A6*B6 - A7*B7;
    float c1 = A0*B1 + A1*B0 - A2*B4 + A4*B2 - A3*B5 + A5*B3 - A6*B7 - A7*B6;
    float c2 = A0*B2 + A2*B0 + A1*B4 - A4*B1 - A3*B6 + A6*B3 + A5*B7 + A7*B5;
    float c3 = A0*B3 + A3*B0 + A1*B5 - A5*B1 + A2*B6 - A6*B2 - A4*B7 - A7*B4;
    float c4 = A0*B4 + A4*B0 + A1*B2 - A2*B1 - A5*B6 + A6*B5 + A3*B7 + A7*B3;
    float c5 = A0*B5 + A5*B0 + A1*B3 - A3*B1 + A4*B6 - A6*B4 - A2*B7 - A7*B2;
    float c6 = A0*B6 + A6*B0 + A2*B3 - A3*B2 - A4*B5 + A5*B4 + A1*B7 + A7*B1;
    float c7 = A0*B7 + A7*B0 + A1*B6 + A6*B1 - A2*B5 - A5*B2 + A3*B4 + A4*B3;

    return hi ? make_float4(c4, c5, c6, c7) : make_float4(c0, c1, c2, c3);
}

__device__ __forceinline__ float4 clifford_plain(float4 fa, float4 fb, bool hi) {
    nfloat4 va = {fa.x, fa.y, fa.z, fa.w};
    nfloat4 vb = {fb.x, fb.y, fb.z, fb.w};
    return clifford_half(va, vb, hi);
}

__global__ __launch_bounds__(256) void CliffordProduct_85452669321821_kernel(
    const float4* __restrict__ a, const float4* __restrict__ b,
    float4* __restrict__ out, int n4) {
    const bool hi = (threadIdx.x & 1);           // odd lane = high half
    const int base = blockIdx.x * 1024 + threadIdx.x;  // 4 x 256 float4/block

    if (base + 768 < n4) {
        const uint32_t off = (uint32_t)base * 16u;
        // 8 loads issued back-to-back: 8 KB in flight per wave, guaranteed.
        nfloat4 va0 = gload(a, off);
        nfloat4 vb0 = gload(b, off);
        nfloat4 va1 = gload(a, off + 4096u);
        nfloat4 vb1 = gload(b, off + 4096u);
        nfloat4 va2 = gload(a, off + 8192u);
        nfloat4 vb2 = gload(b, off + 8192u);
        nfloat4 va3 = gload(a, off + 12288u);
        nfloat4 vb3 = gload(b, off + 12288u);

        // Counted drain: pair k ready when >=2(k+1) oldest ops retired.
        // vmcnt decrements in issue order, so pending younger stores only
        // raise the bound by the number issued so far.
        WAIT_VM(6);                       // va0,vb0 done (8 issued)
        out[base]       = clifford_half(va0, vb0, hi);
        WAIT_VM(5);                       // +store0 issued: <=5 => 4 retired
        out[base + 256] = clifford_half(va1, vb1, hi);
        WAIT_VM(4);                       // <=4 of 10 => 6 retired
        out[base + 512] = clifford_half(va2, vb2, hi);
        WAIT_VM(3);                       // <=3 of 11 => all 8 loads retired
        out[base + 768] = clifford_half(va3, vb3, hi);
    } else {
        // Tail (unused at n4 = 16M, kept for generality): plain HIP path.
        // Pairs (2k,2k+1) share the bounds check, shuffles stay pair-safe.
        #pragma unroll
        for (int u = 0; u < 4; ++u) {
            int idx = base + 256 * u;
            if (idx < n4) out[idx] = clifford_plain(a[idx], b[idx], hi);
        }
    }
}

extern "C" void kernel_launch(void* const* d_in, const int* in_sizes, int n_in,
                              void* d_out, int out_size, void* d_ws, size_t ws_size,
                              hipStream_t stream) {
    const float4* a = (const float4*)d_in[0];
    const float4* b = (const float4*)d_in[1];
    float4* out = (float4*)d_out;
    int n4 = in_sizes[0] / 4;          // total float4 elements (2 per mv)
    int blocks = (n4 + 1023) / 1024;   // one 1024-float4 tile per block
    CliffordProduct_85452669321821_kernel<<<blocks, 256, 0, stream>>>(a, b, out, n4);
}